// Round 33
// baseline (101.185 us; speedup 1.0000x reference)
//
#include <hip/hip_runtime.h>
#include <cstdint>
#include <cstddef>

#define E 32
#define Bsz 64
#define Lsz 2048
#define JCHUNK 128
#define NCH (Lsz / JCHUNK)   // 16
#define JBCH 2               // band halfwidth in chunks; min dropped |i-j|=257 -> m<=0.015, err ~1e-4
#define VSTR 132             // V^T LDS row stride (halfs): word-stride 66 == 2 mod 32 -> uniform 2-way
#define VBUF (32 * VSTR)     // halfs per V buffer
#define MBW 640              // band columns computed per mask row (5 chunks)

typedef float f32x4 __attribute__((ext_vector_type(4)));
typedef float f32x16 __attribute__((ext_vector_type(16)));
typedef __bf16 bf16x8 __attribute__((ext_vector_type(8)));
typedef __bf16 bf16x4 __attribute__((ext_vector_type(4)));
typedef short s16x8 __attribute__((ext_vector_type(8)));
typedef short s16x4 __attribute__((ext_vector_type(4)));
typedef unsigned short u16;

typedef __attribute__((address_space(3))) unsigned int as3_u32;
typedef __attribute__((address_space(1))) const unsigned int as1_u32;

__device__ inline u16 f2bf(float f) {
    union { float f; unsigned u; } x; x.f = f;
    unsigned r = x.u + 0x7FFFu + ((x.u >> 16) & 1u);
    return (u16)(r >> 16);
}
__device__ inline float bf2f(u16 h) {
    union { unsigned u; float f; } x; x.u = ((unsigned)h) << 16;
    return x.f;
}

__device__ inline void glds(const void* g, void* l) {
    __builtin_amdgcn_global_load_lds((as1_u32*)g, (as3_u32*)l, 16, 0, 0);
}

// 32x32x16 bf16 (A 8 bf16, B 8 bf16, C/D 16 f32)
__device__ inline f32x16 qk_mfma(bf16x8 a, bf16x8 b, f32x16 c) {
#if __has_builtin(__builtin_amdgcn_mfma_f32_32x32x16_bf16)
    return __builtin_amdgcn_mfma_f32_32x32x16_bf16(a, b, c, 0, 0, 0);
#else
    asm volatile("s_nop 1\n\tv_mfma_f32_32x32x16_bf16 %0, %1, %2, %0\n\ts_nop 7\n\ts_nop 7"
                 : "+v"(c) : "v"(a), "v"(b));
    return c;
#endif
}
// 32x32x8 bf16 (A 4 bf16, B 4 bf16, C/D 16 f32)
__device__ inline f32x16 pv_mfma8(bf16x4 a, bf16x4 b, f32x16 c) {
#if __has_builtin(__builtin_amdgcn_mfma_f32_32x32x8_bf16)
    return __builtin_amdgcn_mfma_f32_32x32x8_bf16(a, b, c, 0, 0, 0);
#elif __has_builtin(__builtin_amdgcn_mfma_f32_32x32x8bf16_1k)
    return __builtin_amdgcn_mfma_f32_32x32x8bf16_1k(
        __builtin_bit_cast(s16x4, a), __builtin_bit_cast(s16x4, b), c, 0, 0, 0);
#else
    asm volatile("s_nop 1\n\tv_mfma_f32_32x32x8_bf16 %0, %1, %2, %0\n\ts_nop 7\n\ts_nop 7"
                 : "+v"(c) : "v"(a), "v"(b));
    return c;
#endif
}

// ---------------- PSF mask, BAND COLUMNS ONLY, full [2048][2048] layout ----------------
// Row i: compute j = jlo_eff*128 + jb for jb in [0,640), jlo_eff = min(max(0,qb-2),11).
// This 5-chunk window always covers attn's true band [jlo,jhi); each (i,j) written once.
__global__ __launch_bounds__(256) void mask_kernel(u16* __restrict__ M) {
    int g = blockIdx.x * 256 + threadIdx.x;     // < 2048 * 640
    int i = g / MBW;
    int jb = g - i * MBW;
    int qb = i >> 7;
    int jlo_eff = min(max(0, qb - JBCH), NCH - 5);
    int j = jlo_eff * JCHUNK + jb;
    const float scale = 21.0f / 2048.0f;
    float si = fmaxf((i + 0.5f) * scale - 0.5f, 0.f);
    float sj = fmaxf((j + 0.5f) * scale - 0.5f, 0.f);
    int i0 = (int)si; float fi = si - (float)i0;
    int j0 = (int)sj; float fj = sj - (float)j0;
    int i0c = min(i0, 20), i1c = min(i0 + 1, 20);
    int j0c = min(j0, 20), j1c = min(j0 + 1, 20);
    int d00 = abs(i0c - j0c), d01 = abs(i0c - j1c), d10 = abs(i1c - j0c), d11 = abs(i1c - j1c);
    float t00 = __expf(-0.125f * (float)(d00 * d00));
    float t01 = __expf(-0.125f * (float)(d01 * d01));
    float t10 = __expf(-0.125f * (float)(d10 * d10));
    float t11 = __expf(-0.125f * (float)(d11 * d11));
    float m = (1.f - fi) * ((1.f - fj) * t00 + fj * t01)
            + fi * ((1.f - fj) * t10 + fj * t11);
    m = m * (0.17677669529663687f / 5.0132563952f);   // /sqrt(32) / Z — natural scale (poly-exp)
    M[(size_t)i * Lsz + j] = f2bf(m);
}

// ---------------- QKV split into 12 balanced block roles (arithmetic identical) ----------------
// roles 0-3: Q rows [8r, 8r+8).  4-7: K rows.  8-11: V rows + per-eighth chunk V-sums.
// 6144 blocks = 24/CU; each block 8 outputs (one 16B store/thread); per-output FMA chains,
// rounding and Vcs sum order bit-identical to the 6-role version.
__global__ __launch_bounds__(256) void qkv_kernel(const float* __restrict__ x,
        const float* __restrict__ Wqkv, const float* __restrict__ bqkv,
        u16* __restrict__ Q, u16* __restrict__ K, u16* __restrict__ Vt,
        float* __restrict__ Vcs) {
    __shared__ __align__(16) float Wl[8 * 32];
    __shared__ float bl[8];
    __shared__ u16 vsm[256][10];
    int tid = threadIdx.x;
    int blk = blockIdx.x;
    int role = blk >> 9;               // 0..11
    int gb = blk & 511;
    int g = gb * 256 + tid;
    int b = g >> 11, l = g & 2047;
    int eoff = 8 * (role & 3);         // e offset within the 32-wide output group

    if (tid < 8 * 32) Wl[tid] = Wqkv[role * 8 * 32 + tid];
    if (tid < 8) bl[tid] = bqkv[role * 8 + tid];
    __syncthreads();

    float xr[E];
    #pragma unroll
    for (int c = 0; c < E; ++c) xr[c] = x[((size_t)b * E + c) * Lsz + l];

    if (role < 8) {
        u16* dst = (role < 4) ? Q : K;
        s16x8 pk;
        #pragma unroll
        for (int e = 0; e < 8; ++e) {
            float acc = bl[e];
            const f32x4* wrow = (const f32x4*)(Wl + e * E);
            #pragma unroll
            for (int c4 = 0; c4 < 8; ++c4) {
                f32x4 w4 = wrow[c4];
                acc = __builtin_fmaf(xr[4 * c4 + 0], w4[0], acc);
                acc = __builtin_fmaf(xr[4 * c4 + 1], w4[1], acc);
                acc = __builtin_fmaf(xr[4 * c4 + 2], w4[2], acc);
                acc = __builtin_fmaf(xr[4 * c4 + 3], w4[3], acc);
            }
            pk[e] = (short)f2bf(acc);
        }
        *(s16x8*)(dst + ((size_t)b * Lsz + l) * E + eoff) = pk;
    } else {
        #pragma unroll
        for (int e = 0; e < 8; ++e) {
            float acc = bl[e];
            const f32x4* wrow = (const f32x4*)(Wl + e * E);
            #pragma unroll
            for (int c4 = 0; c4 < 8; ++c4) {
                f32x4 w4 = wrow[c4];
                acc = __builtin_fmaf(xr[4 * c4 + 0], w4[0], acc);
                acc = __builtin_fmaf(xr[4 * c4 + 1], w4[1], acc);
                acc = __builtin_fmaf(xr[4 * c4 + 2], w4[2], acc);
                acc = __builtin_fmaf(xr[4 * c4 + 3], w4[3], acc);
            }
            u16 hv = f2bf(acc);
            vsm[tid][e] = hv;
            Vt[((size_t)b * E + eoff + e) * Lsz + l] = hv;
        }
        __syncthreads();
        // chunk V-sums for this eighth's 8 e's: block covers chunks 2*(gb&7) and +1
        if (tid < 16) {
            int cl = tid >> 3, e = tid & 7;
            float s = 0.f;
            #pragma unroll 4
            for (int r = 0; r < 128; ++r) s += bf2f(vsm[cl * 128 + r][e]);
            int chunk = 2 * (gb & 7) + cl;
            Vcs[((size_t)b * NCH + chunk) * 32 + eoff + e] = s;
        }
    }
}

// ---------------- Flash attention + FUSED output projection ----------------
// 1024 blocks (B x L/128) x 256 threads (4 waves x 32 q). Band = chunks [qblk-2, qblk+3).
// Outside band: P = 1 (to tolerance) -> O += sum_out V[e], den += #outside.
// Epilogue: per-wave 32q x 32e LDS transpose -> own 1/dsum -> 16-channel projection.
__global__ __launch_bounds__(256, 4) void attn_kernel(const u16* __restrict__ Q,
        const u16* __restrict__ Kg, const u16* __restrict__ Vt,
        const u16* __restrict__ M, const float* __restrict__ Vcs,
        const float* __restrict__ Wout, const float* __restrict__ bout,
        float* __restrict__ y) {
    extern __shared__ char smem[];
    int blk = blockIdx.x;
    int b = blk >> 4;
    int qblk = blk & 15;
    int tid = threadIdx.x;
    int wave = tid >> 6, lane = tid & 63;
    int lq = lane & 31, hi = lane >> 5;
    int qbase = qblk * 128 + wave * 32;

    const int jlo = max(0, qblk - JBCH);
    const int jhi = min(NCH, qblk + 1 + JBCH);

    const size_t bLE = (size_t)b * Lsz * E;
    const u16* qp = Q + bLE + (size_t)(qbase + lq) * E + hi * 8;
    bf16x8 qf0 = *(const bf16x8*)(qp);
    bf16x8 qf1 = *(const bf16x8*)(qp + 16);
    const u16* mrow = M + (size_t)(qbase + lq) * Lsz + hi * 4;

    // K staging: LDS slot p of row holds K[row][p ^ ((row>>1)&3)] (16B slots)
    const char* kcbase = (const char*)(Kg + bLE);
    int krow = tid >> 2, ks4 = tid & 3;
    int ksrc = krow * 64 + ((ks4 ^ ((krow >> 1) & 3)) << 4);
    u16* smem_h = (u16*)smem;
    u16* vls = smem_h + 8192;     // V region; K = halfs 0..8191 (2 bufs x 4096)

    // V^T staging: thread (ev, sv) covers Vt[b][ev][jc*128 + sv*8 (+64)]
    const u16* vtb = Vt + bLE;
    int ev = tid >> 3, sv = tid & 7;
    size_t vg = (size_t)ev * Lsz + sv * 8;
    int vwo = ev * VSTR + sv * 8;

    f32x16 o = {};
    float dsum = 0.f;

// cubic poly exp: p = ((y/6 + 1/2)y + 1)y + 1, y = s*m  (|y| <~ 0.45; err <= y^4/24)
#define PEXP(s_v, m_v, dst_, di_) do { \
    float y_ = (s_v) * (m_v); \
    float t_ = __builtin_fmaf(y_, 0.16666667f, 0.5f); \
    t_ = __builtin_fmaf(t_, y_, 1.0f); \
    float p_ = __builtin_fmaf(t_, y_, 1.0f); \
    dsum += p_; dst_[di_] = (__bf16)p_; \
} while (0)

#define TILE(jt) do { \
    int kr_ = (jt) * 32 + lq; \
    int sw_ = (kr_ >> 1) & 3; \
    const u16* kp_ = smem_h + buf * 4096 + kr_ * 32; \
    bf16x8 ka0 = *(const bf16x8*)(kp_ + (((hi) ^ sw_) << 3)); \
    bf16x8 ka1 = *(const bf16x8*)(kp_ + (((2 + hi) ^ sw_) << 3)); \
    f32x16 zc = {}; \
    f32x16 s_ = qk_mfma(ka1, qf1, qk_mfma(ka0, qf0, zc)); \
    const u16* mr_ = mrow + jco + (jt) * 32; \
    bf16x4 mm0 = *(const bf16x4*)(mr_); \
    bf16x4 mm1 = *(const bf16x4*)(mr_ + 8); \
    bf16x4 mm2 = *(const bf16x4*)(mr_ + 16); \
    bf16x4 mm3 = *(const bf16x4*)(mr_ + 24); \
    bf16x4 pa0, pa1, pa2, pa3; \
    _Pragma("unroll") for (int c = 0; c < 4; ++c) PEXP(s_[c],      (float)mm0[c], pa0, c); \
    _Pragma("unroll") for (int c = 0; c < 4; ++c) PEXP(s_[4 + c],  (float)mm1[c], pa1, c); \
    _Pragma("unroll") for (int c = 0; c < 4; ++c) PEXP(s_[8 + c],  (float)mm2[c], pa2, c); \
    _Pragma("unroll") for (int c = 0; c < 4; ++c) PEXP(s_[12 + c], (float)mm3[c], pa3, c); \
    const u16* vp_ = vls + buf * VBUF + lq * VSTR + (jt) * 32 + hi * 4; \
    bf16x4 vf0 = *(const bf16x4*)(vp_); \
    bf16x4 vf1 = *(const bf16x4*)(vp_ + 8); \
    bf16x4 vf2 = *(const bf16x4*)(vp_ + 16); \
    bf16x4 vf3 = *(const bf16x4*)(vp_ + 24); \
    o = pv_mfma8(pa0, vf0, o); \
    o = pv_mfma8(pa1, vf1, o); \
    o = pv_mfma8(pa2, vf2, o); \
    o = pv_mfma8(pa3, vf3, o); \
} while (0)

    int buf = 0;
    {   // prologue: stage first band chunk
        const char* kc = kcbase + (size_t)jlo * 8192;
        glds(kc + ksrc, smem + wave * 1024);
        glds(kc + ksrc + 4096, smem + 4096 + wave * 1024);
        s16x8 va = *(const s16x8*)(vtb + vg + (size_t)jlo * JCHUNK);
        s16x8 vb = *(const s16x8*)(vtb + vg + (size_t)jlo * JCHUNK + 64);
        u16* vd = vls + vwo;
        *(s16x4*)(vd)          = (s16x4){va[0], va[1], va[2], va[3]};
        *(s16x4*)(vd + 4)      = (s16x4){va[4], va[5], va[6], va[7]};
        *(s16x4*)(vd + 64)     = (s16x4){vb[0], vb[1], vb[2], vb[3]};
        *(s16x4*)(vd + 64 + 4) = (s16x4){vb[4], vb[5], vb[6], vb[7]};
        __syncthreads();
    }
    #pragma unroll 1
    for (int jc = jlo; jc < jhi; ++jc) {
        s16x8 va = {}, vb = {};
        if (jc + 1 < jhi) {
            const char* kc = kcbase + (size_t)(jc + 1) * 8192;
            glds(kc + ksrc, smem + (buf ^ 1) * 8192 + wave * 1024);
            glds(kc + ksrc + 4096, smem + (buf ^ 1) * 8192 + 4096 + wave * 1024);
            va = *(const s16x8*)(vtb + vg + (size_t)(jc + 1) * JCHUNK);
            vb = *(const s16x8*)(vtb + vg + (size_t)(jc + 1) * JCHUNK + 64);
        }
        const int jco = jc * JCHUNK;
        __builtin_amdgcn_s_setprio(1);
        TILE(0); TILE(1); TILE(2); TILE(3);
        __builtin_amdgcn_s_setprio(0);
        if (jc + 1 < jhi) {
            u16* vd = vls + (buf ^ 1) * VBUF + vwo;
            *(s16x4*)(vd)          = (s16x4){va[0], va[1], va[2], va[3]};
            *(s16x4*)(vd + 4)      = (s16x4){va[4], va[5], va[6], va[7]};
            *(s16x4*)(vd + 64)     = (s16x4){vb[0], vb[1], vb[2], vb[3]};
            *(s16x4*)(vd + 64 + 4) = (s16x4){vb[4], vb[5], vb[6], vb[7]};
        }
        __syncthreads();
        buf ^= 1;
    }
#undef TILE
#undef PEXP

    // outside-band V sum for e=lq and the outside count
    float vout = 0.f;
    #pragma unroll 1
    for (int c = 0; c < NCH; ++c)
        if (c < jlo || c >= jhi) vout += Vcs[((size_t)b * NCH + c) * 32 + lq];
    dsum += __shfl_xor(dsum, 32);
    dsum += (float)(JCHUNK * (NCH - (jhi - jlo)));
    float inv = 1.0f / dsum;       // this lane's q = lq

    // ---- fused output projection (K/V LDS regions are dead after the final barrier) ----
    float* Wl  = (float*)(smem + 16896);          // 32x32 f32 = 4096 B
    float* blz = Wl + 32 * 32;                    // 32 f32
    for (int i = tid; i < 32 * 32; i += 256) Wl[i] = Wout[i];
    if (tid < 32) blz[tid] = bout[tid];
    // per-wave O-tile [32 q][33] f32 at smem + wave*4224
    float* otile = (float*)smem + wave * (32 * 33);
    #pragma unroll
    for (int r = 0; r < 16; ++r) {
        int qr = (r & 3) + 8 * (r >> 2) + 4 * hi;
        otile[qr * 33 + lq] = o[r] + vout;        // O[q=qr][e=lq], unnormalized
    }
    __syncthreads();                              // W/bias visible (O-tile is same-wave)
    float orow[E];
    #pragma unroll
    for (int e = 0; e < E; ++e) orow[e] = otile[lq * 33 + e] * inv;   // row q=lq, own inv
    int qg = qbase + lq;
    #pragma unroll
    for (int cc = 0; cc < 16; ++cc) {
        int c = hi * 16 + cc;
        float acc = blz[c];
        const f32x4* wrow = (const f32x4*)(Wl + c * E);
        #pragma unroll
        for (int e4 = 0; e4 < 8; ++e4) {
            f32x4 w4 = wrow[e4];
            acc = __builtin_fmaf(orow[4 * e4 + 0], w4[0], acc);
            acc = __builtin_fmaf(orow[4 * e4 + 1], w4[1], acc);
            acc = __builtin_fmaf(orow[4 * e4 + 2], w4[2], acc);
            acc = __builtin_fmaf(orow[4 * e4 + 3], w4[3], acc);
        }
        y[((size_t)b * E + c) * Lsz + qg] = acc;
    }
}

extern "C" void kernel_launch(void* const* d_in, const int* in_sizes, int n_in,
                              void* d_out, int out_size, void* d_ws, size_t ws_size,
                              hipStream_t stream) {
    const float* x    = (const float*)d_in[0];
    const float* Wqkv = (const float*)d_in[1];
    const float* bqkv = (const float*)d_in[2];
    const float* Wout = (const float*)d_in[3];
    const float* bout = (const float*)d_in[4];
    float* y = (float*)d_out;

    char* ws = (char*)d_ws;
    const size_t szQ  = (size_t)Bsz * Lsz * E * sizeof(u16);   // 8.39 MB
    const size_t szM  = (size_t)Lsz * Lsz * sizeof(u16);       // 8.39 MB
    u16* Q     = (u16*)(ws);
    u16* K     = (u16*)(ws + szQ);
    u16* Vt    = (u16*)(ws + 2 * szQ);
    u16* M     = (u16*)(ws + 3 * szQ);
    float* Vcs = (float*)(ws + 3 * szQ + szM);                 // 128 KB

    const int lds_bytes = 16384 + 2 * VBUF * 2;                // K dbuf + V dbuf = 33280

    hipLaunchKernelGGL(mask_kernel, dim3((Lsz * MBW) / 256), dim3(256), 0, stream, M);
    hipLaunchKernelGGL(qkv_kernel, dim3(12 * 512), dim3(256), 0, stream,
                       x, Wqkv, bqkv, Q, K, Vt, Vcs);
    hipLaunchKernelGGL(attn_kernel, dim3(Bsz * (Lsz / 128)), dim3(256), lds_bytes, stream,
                       Q, K, Vt, M, Vcs, Wout, bout, y);
}

// Round 34
// 94.516 us; speedup vs baseline: 1.0706x; 1.0706x over previous
//
#include <hip/hip_runtime.h>
#include <cstdint>
#include <cstddef>

#define E 32
#define Bsz 64
#define Lsz 2048
#define JCHUNK 128
#define NCH (Lsz / JCHUNK)   // 16
#define JBCH 2               // band halfwidth in chunks; min dropped |i-j|=257 -> m<=0.015, err ~1e-4
#define VSTR 132             // V^T LDS row stride (halfs): word-stride 66 == 2 mod 32 -> uniform 2-way
#define VBUF (32 * VSTR)     // halfs per V buffer
#define MBW 640              // band columns computed per mask row (5 chunks)

typedef float f32x4 __attribute__((ext_vector_type(4)));
typedef float f32x16 __attribute__((ext_vector_type(16)));
typedef __bf16 bf16x8 __attribute__((ext_vector_type(8)));
typedef __bf16 bf16x4 __attribute__((ext_vector_type(4)));
typedef short s16x8 __attribute__((ext_vector_type(8)));
typedef short s16x4 __attribute__((ext_vector_type(4)));
typedef unsigned short u16;

typedef __attribute__((address_space(3))) unsigned int as3_u32;
typedef __attribute__((address_space(1))) const unsigned int as1_u32;

__device__ inline u16 f2bf(float f) {
    union { float f; unsigned u; } x; x.f = f;
    unsigned r = x.u + 0x7FFFu + ((x.u >> 16) & 1u);
    return (u16)(r >> 16);
}
__device__ inline float bf2f(u16 h) {
    union { unsigned u; float f; } x; x.u = ((unsigned)h) << 16;
    return x.f;
}

__device__ inline void glds(const void* g, void* l) {
    __builtin_amdgcn_global_load_lds((as1_u32*)g, (as3_u32*)l, 16, 0, 0);
}

// 32x32x16 bf16 (A 8 bf16, B 8 bf16, C/D 16 f32)
__device__ inline f32x16 qk_mfma(bf16x8 a, bf16x8 b, f32x16 c) {
#if __has_builtin(__builtin_amdgcn_mfma_f32_32x32x16_bf16)
    return __builtin_amdgcn_mfma_f32_32x32x16_bf16(a, b, c, 0, 0, 0);
#else
    asm volatile("s_nop 1\n\tv_mfma_f32_32x32x16_bf16 %0, %1, %2, %0\n\ts_nop 7\n\ts_nop 7"
                 : "+v"(c) : "v"(a), "v"(b));
    return c;
#endif
}
// 32x32x8 bf16 (A 4 bf16, B 4 bf16, C/D 16 f32)
__device__ inline f32x16 pv_mfma8(bf16x4 a, bf16x4 b, f32x16 c) {
#if __has_builtin(__builtin_amdgcn_mfma_f32_32x32x8_bf16)
    return __builtin_amdgcn_mfma_f32_32x32x8_bf16(a, b, c, 0, 0, 0);
#elif __has_builtin(__builtin_amdgcn_mfma_f32_32x32x8bf16_1k)
    return __builtin_amdgcn_mfma_f32_32x32x8bf16_1k(
        __builtin_bit_cast(s16x4, a), __builtin_bit_cast(s16x4, b), c, 0, 0, 0);
#else
    asm volatile("s_nop 1\n\tv_mfma_f32_32x32x8_bf16 %0, %1, %2, %0\n\ts_nop 7\n\ts_nop 7"
                 : "+v"(c) : "v"(a), "v"(b));
    return c;
#endif
}

// ---------------- PSF mask, BAND COLUMNS ONLY, full [2048][2048] layout ----------------
// Row i: compute j = jlo_eff*128 + jb for jb in [0,640), jlo_eff = min(max(0,qb-2),11).
// This 5-chunk window always covers attn's true band [jlo,jhi); each (i,j) written once.
__global__ __launch_bounds__(256) void mask_kernel(u16* __restrict__ M) {
    int g = blockIdx.x * 256 + threadIdx.x;     // < 2048 * 640
    int i = g / MBW;
    int jb = g - i * MBW;
    int qb = i >> 7;
    int jlo_eff = min(max(0, qb - JBCH), NCH - 5);
    int j = jlo_eff * JCHUNK + jb;
    const float scale = 21.0f / 2048.0f;
    float si = fmaxf((i + 0.5f) * scale - 0.5f, 0.f);
    float sj = fmaxf((j + 0.5f) * scale - 0.5f, 0.f);
    int i0 = (int)si; float fi = si - (float)i0;
    int j0 = (int)sj; float fj = sj - (float)j0;
    int i0c = min(i0, 20), i1c = min(i0 + 1, 20);
    int j0c = min(j0, 20), j1c = min(j0 + 1, 20);
    int d00 = abs(i0c - j0c), d01 = abs(i0c - j1c), d10 = abs(i1c - j0c), d11 = abs(i1c - j1c);
    float t00 = __expf(-0.125f * (float)(d00 * d00));
    float t01 = __expf(-0.125f * (float)(d01 * d01));
    float t10 = __expf(-0.125f * (float)(d10 * d10));
    float t11 = __expf(-0.125f * (float)(d11 * d11));
    float m = (1.f - fi) * ((1.f - fj) * t00 + fj * t01)
            + fi * ((1.f - fj) * t10 + fj * t11);
    m = m * (0.17677669529663687f / 5.0132563952f);   // /sqrt(32) / Z — natural scale (poly-exp)
    M[(size_t)i * Lsz + j] = f2bf(m);
}

// ---------------- QKV split into 6 balanced block roles (arithmetic identical) ----------------
// roles 0-1: Q rows [0,16)/[16,32).  2-3: K rows [32,48)/[48,64).  4-5: V rows [64,80)/
// [80,96) + per-half chunk V-sums.  3072 blocks = 12/CU; each block 16 outputs; per-output
// FMA chains, rounding and Vcs sum order bit-identical to the 3-role version.
__global__ __launch_bounds__(256) void qkv_kernel(const float* __restrict__ x,
        const float* __restrict__ Wqkv, const float* __restrict__ bqkv,
        u16* __restrict__ Q, u16* __restrict__ K, u16* __restrict__ Vt,
        float* __restrict__ Vcs) {
    __shared__ __align__(16) float Wl[16 * 32];
    __shared__ float bl[16];
    __shared__ u16 vsm[256][18];
    int tid = threadIdx.x;
    int blk = blockIdx.x;
    int role = blk >> 9;               // 0..5
    int gb = blk & 511;
    int g = gb * 256 + tid;
    int b = g >> 11, l = g & 2047;
    int eoff = 16 * (role & 1);        // e offset within the 32-wide output group

    for (int i = tid; i < 16 * 32; i += 256) Wl[i] = Wqkv[role * 16 * 32 + i];
    if (tid < 16) bl[tid] = bqkv[role * 16 + tid];
    __syncthreads();

    float xr[E];
    #pragma unroll
    for (int c = 0; c < E; ++c) xr[c] = x[((size_t)b * E + c) * Lsz + l];

    if (role < 4) {
        u16* dst = (role < 2) ? Q : K;
        s16x8 pk[2];
        #pragma unroll
        for (int e = 0; e < 16; ++e) {
            float acc = bl[e];
            const f32x4* wrow = (const f32x4*)(Wl + e * E);
            #pragma unroll
            for (int c4 = 0; c4 < 8; ++c4) {
                f32x4 w4 = wrow[c4];
                acc = __builtin_fmaf(xr[4 * c4 + 0], w4[0], acc);
                acc = __builtin_fmaf(xr[4 * c4 + 1], w4[1], acc);
                acc = __builtin_fmaf(xr[4 * c4 + 2], w4[2], acc);
                acc = __builtin_fmaf(xr[4 * c4 + 3], w4[3], acc);
            }
            pk[e >> 3][e & 7] = (short)f2bf(acc);
        }
        s16x8* dp = (s16x8*)(dst + ((size_t)b * Lsz + l) * E + eoff);
        dp[0] = pk[0];
        dp[1] = pk[1];
    } else {
        #pragma unroll
        for (int e = 0; e < 16; ++e) {
            float acc = bl[e];
            const f32x4* wrow = (const f32x4*)(Wl + e * E);
            #pragma unroll
            for (int c4 = 0; c4 < 8; ++c4) {
                f32x4 w4 = wrow[c4];
                acc = __builtin_fmaf(xr[4 * c4 + 0], w4[0], acc);
                acc = __builtin_fmaf(xr[4 * c4 + 1], w4[1], acc);
                acc = __builtin_fmaf(xr[4 * c4 + 2], w4[2], acc);
                acc = __builtin_fmaf(xr[4 * c4 + 3], w4[3], acc);
            }
            u16 hv = f2bf(acc);
            vsm[tid][e] = hv;
            Vt[((size_t)b * E + eoff + e) * Lsz + l] = hv;
        }
        __syncthreads();
        // chunk V-sums for this half's 16 e's: block covers chunks 2*(gb&7) and +1
        if (tid < 32) {
            int cl = tid >> 4, e = tid & 15;
            float s = 0.f;
            #pragma unroll 4
            for (int r = 0; r < 128; ++r) s += bf2f(vsm[cl * 128 + r][e]);
            int chunk = 2 * (gb & 7) + cl;
            Vcs[((size_t)b * NCH + chunk) * 32 + eoff + e] = s;
        }
    }
}

// ---------------- Flash attention + FUSED output projection ----------------
// 1024 blocks (B x L/128) x 256 threads (4 waves x 32 q). Band = chunks [qblk-2, qblk+3).
// Outside band: P = 1 (to tolerance) -> O += sum_out V[e], den += #outside.
// Epilogue: per-wave 32q x 32e LDS transpose -> own 1/dsum -> 16-channel projection.
__global__ __launch_bounds__(256, 4) void attn_kernel(const u16* __restrict__ Q,
        const u16* __restrict__ Kg, const u16* __restrict__ Vt,
        const u16* __restrict__ M, const float* __restrict__ Vcs,
        const float* __restrict__ Wout, const float* __restrict__ bout,
        float* __restrict__ y) {
    extern __shared__ char smem[];
    int blk = blockIdx.x;
    int b = blk >> 4;
    int qblk = blk & 15;
    int tid = threadIdx.x;
    int wave = tid >> 6, lane = tid & 63;
    int lq = lane & 31, hi = lane >> 5;
    int qbase = qblk * 128 + wave * 32;

    const int jlo = max(0, qblk - JBCH);
    const int jhi = min(NCH, qblk + 1 + JBCH);

    const size_t bLE = (size_t)b * Lsz * E;
    const u16* qp = Q + bLE + (size_t)(qbase + lq) * E + hi * 8;
    bf16x8 qf0 = *(const bf16x8*)(qp);
    bf16x8 qf1 = *(const bf16x8*)(qp + 16);
    const u16* mrow = M + (size_t)(qbase + lq) * Lsz + hi * 4;

    // K staging: LDS slot p of row holds K[row][p ^ ((row>>1)&3)] (16B slots)
    const char* kcbase = (const char*)(Kg + bLE);
    int krow = tid >> 2, ks4 = tid & 3;
    int ksrc = krow * 64 + ((ks4 ^ ((krow >> 1) & 3)) << 4);
    u16* smem_h = (u16*)smem;
    u16* vls = smem_h + 8192;     // V region; K = halfs 0..8191 (2 bufs x 4096)

    // V^T staging: thread (ev, sv) covers Vt[b][ev][jc*128 + sv*8 (+64)]
    const u16* vtb = Vt + bLE;
    int ev = tid >> 3, sv = tid & 7;
    size_t vg = (size_t)ev * Lsz + sv * 8;
    int vwo = ev * VSTR + sv * 8;

    f32x16 o = {};
    float dsum = 0.f;

// cubic poly exp: p = ((y/6 + 1/2)y + 1)y + 1, y = s*m  (|y| <~ 0.45; err <= y^4/24)
#define PEXP(s_v, m_v, dst_, di_) do { \
    float y_ = (s_v) * (m_v); \
    float t_ = __builtin_fmaf(y_, 0.16666667f, 0.5f); \
    t_ = __builtin_fmaf(t_, y_, 1.0f); \
    float p_ = __builtin_fmaf(t_, y_, 1.0f); \
    dsum += p_; dst_[di_] = (__bf16)p_; \
} while (0)

#define TILE(jt) do { \
    int kr_ = (jt) * 32 + lq; \
    int sw_ = (kr_ >> 1) & 3; \
    const u16* kp_ = smem_h + buf * 4096 + kr_ * 32; \
    bf16x8 ka0 = *(const bf16x8*)(kp_ + (((hi) ^ sw_) << 3)); \
    bf16x8 ka1 = *(const bf16x8*)(kp_ + (((2 + hi) ^ sw_) << 3)); \
    f32x16 zc = {}; \
    f32x16 s_ = qk_mfma(ka1, qf1, qk_mfma(ka0, qf0, zc)); \
    const u16* mr_ = mrow + jco + (jt) * 32; \
    bf16x4 mm0 = *(const bf16x4*)(mr_); \
    bf16x4 mm1 = *(const bf16x4*)(mr_ + 8); \
    bf16x4 mm2 = *(const bf16x4*)(mr_ + 16); \
    bf16x4 mm3 = *(const bf16x4*)(mr_ + 24); \
    bf16x4 pa0, pa1, pa2, pa3; \
    _Pragma("unroll") for (int c = 0; c < 4; ++c) PEXP(s_[c],      (float)mm0[c], pa0, c); \
    _Pragma("unroll") for (int c = 0; c < 4; ++c) PEXP(s_[4 + c],  (float)mm1[c], pa1, c); \
    _Pragma("unroll") for (int c = 0; c < 4; ++c) PEXP(s_[8 + c],  (float)mm2[c], pa2, c); \
    _Pragma("unroll") for (int c = 0; c < 4; ++c) PEXP(s_[12 + c], (float)mm3[c], pa3, c); \
    const u16* vp_ = vls + buf * VBUF + lq * VSTR + (jt) * 32 + hi * 4; \
    bf16x4 vf0 = *(const bf16x4*)(vp_); \
    bf16x4 vf1 = *(const bf16x4*)(vp_ + 8); \
    bf16x4 vf2 = *(const bf16x4*)(vp_ + 16); \
    bf16x4 vf3 = *(const bf16x4*)(vp_ + 24); \
    o = pv_mfma8(pa0, vf0, o); \
    o = pv_mfma8(pa1, vf1, o); \
    o = pv_mfma8(pa2, vf2, o); \
    o = pv_mfma8(pa3, vf3, o); \
} while (0)

    int buf = 0;
    {   // prologue: stage first band chunk
        const char* kc = kcbase + (size_t)jlo * 8192;
        glds(kc + ksrc, smem + wave * 1024);
        glds(kc + ksrc + 4096, smem + 4096 + wave * 1024);
        s16x8 va = *(const s16x8*)(vtb + vg + (size_t)jlo * JCHUNK);
        s16x8 vb = *(const s16x8*)(vtb + vg + (size_t)jlo * JCHUNK + 64);
        u16* vd = vls + vwo;
        *(s16x4*)(vd)          = (s16x4){va[0], va[1], va[2], va[3]};
        *(s16x4*)(vd + 4)      = (s16x4){va[4], va[5], va[6], va[7]};
        *(s16x4*)(vd + 64)     = (s16x4){vb[0], vb[1], vb[2], vb[3]};
        *(s16x4*)(vd + 64 + 4) = (s16x4){vb[4], vb[5], vb[6], vb[7]};
        __syncthreads();
    }
    #pragma unroll 1
    for (int jc = jlo; jc < jhi; ++jc) {
        s16x8 va = {}, vb = {};
        if (jc + 1 < jhi) {
            const char* kc = kcbase + (size_t)(jc + 1) * 8192;
            glds(kc + ksrc, smem + (buf ^ 1) * 8192 + wave * 1024);
            glds(kc + ksrc + 4096, smem + (buf ^ 1) * 8192 + 4096 + wave * 1024);
            va = *(const s16x8*)(vtb + vg + (size_t)(jc + 1) * JCHUNK);
            vb = *(const s16x8*)(vtb + vg + (size_t)(jc + 1) * JCHUNK + 64);
        }
        const int jco = jc * JCHUNK;
        __builtin_amdgcn_s_setprio(1);
        TILE(0); TILE(1); TILE(2); TILE(3);
        __builtin_amdgcn_s_setprio(0);
        if (jc + 1 < jhi) {
            u16* vd = vls + (buf ^ 1) * VBUF + vwo;
            *(s16x4*)(vd)          = (s16x4){va[0], va[1], va[2], va[3]};
            *(s16x4*)(vd + 4)      = (s16x4){va[4], va[5], va[6], va[7]};
            *(s16x4*)(vd + 64)     = (s16x4){vb[0], vb[1], vb[2], vb[3]};
            *(s16x4*)(vd + 64 + 4) = (s16x4){vb[4], vb[5], vb[6], vb[7]};
        }
        __syncthreads();
        buf ^= 1;
    }
#undef TILE
#undef PEXP

    // outside-band V sum for e=lq and the outside count
    float vout = 0.f;
    #pragma unroll 1
    for (int c = 0; c < NCH; ++c)
        if (c < jlo || c >= jhi) vout += Vcs[((size_t)b * NCH + c) * 32 + lq];
    dsum += __shfl_xor(dsum, 32);
    dsum += (float)(JCHUNK * (NCH - (jhi - jlo)));
    float inv = 1.0f / dsum;       // this lane's q = lq

    // ---- fused output projection (K/V LDS regions are dead after the final barrier) ----
    float* Wl  = (float*)(smem + 16896);          // 32x32 f32 = 4096 B
    float* blz = Wl + 32 * 32;                    // 32 f32
    for (int i = tid; i < 32 * 32; i += 256) Wl[i] = Wout[i];
    if (tid < 32) blz[tid] = bout[tid];
    // per-wave O-tile [32 q][33] f32 at smem + wave*4224
    float* otile = (float*)smem + wave * (32 * 33);
    #pragma unroll
    for (int r = 0; r < 16; ++r) {
        int qr = (r & 3) + 8 * (r >> 2) + 4 * hi;
        otile[qr * 33 + lq] = o[r] + vout;        // O[q=qr][e=lq], unnormalized
    }
    __syncthreads();                              // W/bias visible (O-tile is same-wave)
    float orow[E];
    #pragma unroll
    for (int e = 0; e < E; ++e) orow[e] = otile[lq * 33 + e] * inv;   // row q=lq, own inv
    int qg = qbase + lq;
    #pragma unroll
    for (int cc = 0; cc < 16; ++cc) {
        int c = hi * 16 + cc;
        float acc = blz[c];
        const f32x4* wrow = (const f32x4*)(Wl + c * E);
        #pragma unroll
        for (int e4 = 0; e4 < 8; ++e4) {
            f32x4 w4 = wrow[e4];
            acc = __builtin_fmaf(orow[4 * e4 + 0], w4[0], acc);
            acc = __builtin_fmaf(orow[4 * e4 + 1], w4[1], acc);
            acc = __builtin_fmaf(orow[4 * e4 + 2], w4[2], acc);
            acc = __builtin_fmaf(orow[4 * e4 + 3], w4[3], acc);
        }
        y[((size_t)b * E + c) * Lsz + qg] = acc;
    }
}

extern "C" void kernel_launch(void* const* d_in, const int* in_sizes, int n_in,
                              void* d_out, int out_size, void* d_ws, size_t ws_size,
                              hipStream_t stream) {
    const float* x    = (const float*)d_in[0];
    const float* Wqkv = (const float*)d_in[1];
    const float* bqkv = (const float*)d_in[2];
    const float* Wout = (const float*)d_in[3];
    const float* bout = (const float*)d_in[4];
    float* y = (float*)d_out;

    char* ws = (char*)d_ws;
    const size_t szQ  = (size_t)Bsz * Lsz * E * sizeof(u16);   // 8.39 MB
    const size_t szM  = (size_t)Lsz * Lsz * sizeof(u16);       // 8.39 MB
    u16* Q     = (u16*)(ws);
    u16* K     = (u16*)(ws + szQ);
    u16* Vt    = (u16*)(ws + 2 * szQ);
    u16* M     = (u16*)(ws + 3 * szQ);
    float* Vcs = (float*)(ws + 3 * szQ + szM);                 // 128 KB

    const int lds_bytes = 16384 + 2 * VBUF * 2;                // K dbuf + V dbuf = 33280

    hipLaunchKernelGGL(mask_kernel, dim3((Lsz * MBW) / 256), dim3(256), 0, stream, M);
    hipLaunchKernelGGL(qkv_kernel, dim3(6 * 512), dim3(256), 0, stream,
                       x, Wqkv, bqkv, Q, K, Vt, Vcs);
    hipLaunchKernelGGL(attn_kernel, dim3(Bsz * (Lsz / 128)), dim3(256), lds_bytes, stream,
                       Q, K, Vt, M, Vcs, Wout, bout, y);
}